// Round 20
// baseline (360.404 us; speedup 1.0000x reference)
//
#include <hip/hip_runtime.h>
#include <math.h>

#define MUL 32
#define NATTR 4
#define NBASIS 10
#define HID 64
#define OUT_DIM 16
#define NGRAPH 8

#define PI_F 3.14159265358979323846f
#define SQRT3_F 1.7320508075688772f
#define INV_SQRT3_F 0.5773502691896258f
#define INV_SQRT10_F 0.31622776601683794f
#define INV_SQRTNN_F 0.17677669529663687f   // 1/sqrt(32)
#define NORM128_F 0.08838834764831845f      // 1/sqrt(128)
#define NORM256_F 0.0625f                   // 1/sqrt(256)
#define C_S_F 0.3826834323650898f           // sin(pi/8)
#define C_X_F 0.9238795325112867f           // cos(pi/8)
#define CSTEP_F (4.0f/9.0f)                 // linspace(0,4,10) step

#define HS 72    // bf16 row stride (shorts): 64 + 8 pad -> 144B, 16B-aligned

typedef __attribute__((ext_vector_type(8))) short bf16x8;
typedef __attribute__((ext_vector_type(4))) float f32x4;

__device__ inline unsigned short f2bf(float x) {
    unsigned u = __float_as_uint(x);
    u += 0x7FFF + ((u >> 16) & 1);          // round-to-nearest-even
    return (unsigned short)(u >> 16);
}
__device__ inline float bf2f(unsigned short h) {
    return __uint_as_float(((unsigned)h) << 16);
}

// ---------------------------------------------------------------- init s,v
__global__ void init_sv(const float* __restrict__ x,
                        float* __restrict__ s, float* __restrict__ v, int N) {
    int i = blockIdx.x * 256 + threadIdx.x;
    if (i >= N * 128) return;
    int n = i >> 7, c = i & 127;
    float val = x[i];
    if (c < 32) s[n * 32 + c] = val;
    else        v[n * 96 + (c - 32)] = val;
}

// ---------------------------------------------------------------- weight setup
__global__ void setup_weights(const float* __restrict__ Wfc2,
                              const float* __restrict__ Wsc0, const float* __restrict__ Wl10,
                              const float* __restrict__ Wsc1, const float* __restrict__ Wl11,
                              const float* __restrict__ Wl20, const float* __restrict__ Wl21,
                              unsigned* __restrict__ wt_g,
                              float* __restrict__ Wfp, unsigned* __restrict__ Wupk) {
    int i = blockIdx.x * 256 + threadIdx.x;
    if (i < 8192) {
        int l = i >> 12, j = i & 4095;
        int wq = j >> 5, kp = j & 31;
        const float* W = Wfc2 + l * 8192;
        unsigned lo = f2bf(W[(2 * kp) * 128 + wq]);
        unsigned hi = f2bf(W[(2 * kp + 1) * 128 + wq]);
        wt_g[i] = lo | (hi << 16);
    } else if (i < 40960) {
        int j = i - 8192;
        int idx = j >> 12;          // l*4 + m, 0..7
        int r = j & 4095;
        int l = idx >> 2, m = idx & 3;
        const float* base = (m == 0 ? Wsc0 : m == 1 ? Wl10 : m == 2 ? Wsc1 : Wl11)
                            + l * 4096;
        int u = r >> 7, rr = r & 127, a = rr >> 5, ww = rr & 31;
        Wfp[idx * 4096 + u * 128 + ww * 4 + a] = base[r];
    } else if (i < 57344) {
        int j = i - 40960;
        int l = j >> 13;            // layer
        int r = j & 8191;
        int u = r >> 7, rr = r & 127, a = rr >> 5, ww = rr & 31;
        unsigned lo = f2bf(Wl20[l * 8192 + r]);
        unsigned hi = f2bf(Wl21[l * 8192 + r]);
        Wupk[l * 8192 + u * 128 + ww * 4 + a] = lo | (hi << 16);
    }
}

// ---------------------------------------------------------------- CSR build
__global__ void csr_count(const int* __restrict__ edst, int* __restrict__ cnt, int E) {
    int e = blockIdx.x * 256 + threadIdx.x;
    if (e < E) atomicAdd(&cnt[edst[e]], 1);
}

__global__ void csr_scan(const int* __restrict__ cnt, int* __restrict__ off,
                         int* __restrict__ cursor, int N) {
    __shared__ int sums[256];
    int t = threadIdx.x;
    int chunk = (N + 255) / 256;
    int lo = t * chunk, hi = lo + chunk; if (hi > N) hi = N;
    int s = 0;
    for (int i = lo; i < hi; i++) s += cnt[i];
    sums[t] = s;
    __syncthreads();
    for (int d = 1; d < 256; d <<= 1) {
        int v = (t >= d) ? sums[t - d] : 0;
        __syncthreads();
        sums[t] += v;
        __syncthreads();
    }
    int run = (t == 0) ? 0 : sums[t - 1];
    for (int i = lo; i < hi; i++) {
        off[i] = run; cursor[i] = run;
        run += cnt[i];
    }
}

__global__ void csr_fill(const int* __restrict__ edst, const int* __restrict__ esrc,
                         const float* __restrict__ edge_vec,
                         int* __restrict__ cursor,
                         float* __restrict__ vec_csr, int E) {
    int e = blockIdx.x * 256 + threadIdx.x;
    if (e < E) {
        int p = atomicAdd(&cursor[edst[e]], 1);
        float4 vv = {edge_vec[e * 3 + 0], edge_vec[e * 3 + 1], edge_vec[e * 3 + 2],
                     __int_as_float(esrc[e])};
        *(float4*)(vec_csr + (size_t)p * 4) = vv;
    }
}

// ---------------------------------------------------------------- bodies
// edge_weights body: 128 CSR slots per block; smem layout:
//   [0,2560) wfc1 | [2560,3072) len | [3072,21504) sh_h | [21504,39936) sh_wt
__device__ __forceinline__ void edge_weights_body(
    int blk, const float* __restrict__ vec_csr,
    const float* __restrict__ Wfc1, const unsigned* __restrict__ wt_g,
    unsigned* __restrict__ w2_buf, int E, char* smem) {
    float* sh_wfc1 = (float*)smem;
    float* sh_len  = (float*)(smem + 2560);
    short* sh_h    = (short*)(smem + 3072);
    short* sh_wt   = (short*)(smem + 21504);

    int tid = threadIdx.x;
    int e0 = blk * 128;

    for (int i = tid; i < 640; i += 256) sh_wfc1[i] = Wfc1[i];
    for (int i = tid; i < 4096; i += 256) {
        ((unsigned*)sh_wt)[(i >> 5) * 36 + (i & 31)] = wt_g[i];
    }
    if (tid < 128) {
        int e = e0 + tid;
        float ex = 0.f, ey = 0.f, ez = 0.f;
        if (e < E) {
            float4 vv = *(const float4*)(vec_csr + (size_t)e * 4);
            ex = vv.x; ey = vv.y; ez = vv.z;
        }
        sh_len[tid] = sqrtf(ex * ex + ey * ey + ez * ez);
    }
    __syncthreads();

    {   // phase 1
        int e = tid >> 1;
        int kg = tid & 1;
        float len = sh_len[e];
        float uu = 2.0f * (len * 0.25f - 1.0f);
        float cut = (uu > 0.0f) ? 0.0f
                  : ((uu < -1.0f) ? 1.0f : 0.5f * (1.0f - __cosf(PI_F * uu)));
        float emb[NBASIS];
#pragma unroll
        for (int j = 0; j < NBASIS; j++) {
            float d = (len - j * CSTEP_F) * 2.5f;
            emb[j] = __expf(-d * d) * cut;
        }
        float acc[32];
#pragma unroll
        for (int i = 0; i < 32; i++) acc[i] = 0.f;
#pragma unroll
        for (int j = 0; j < NBASIS; j++) {
            float ej = emb[j];
            const float* wrow = sh_wfc1 + j * 64 + kg * 32;
#pragma unroll
            for (int i = 0; i < 32; i++) acc[i] += ej * wrow[i];
        }
        unsigned* hrow = (unsigned*)(sh_h + e * HS + kg * 32);
#pragma unroll
        for (int i = 0; i < 16; i++) {
            float a0 = acc[2 * i]     * INV_SQRT10_F;
            float a1 = acc[2 * i + 1] * INV_SQRT10_F;
            float h0 = a0 / (1.0f + __expf(-a0));
            float h1 = a1 / (1.0f + __expf(-a1));
            hrow[i] = (unsigned)f2bf(h0) | ((unsigned)f2bf(h1) << 16);
        }
    }
    __syncthreads();

    {   // phase 2 (MFMA)
        int wave = tid >> 6, lane = tid & 63;
        int m16 = lane & 15, quad = lane >> 4;
        bf16x8 afr[2][2];
#pragma unroll
        for (int mt = 0; mt < 2; mt++)
#pragma unroll
            for (int ks = 0; ks < 2; ks++) {
                int e = wave * 32 + mt * 16 + m16;
                afr[mt][ks] = *(const bf16x8*)(sh_h + e * HS + ks * 32 + quad * 8);
            }
#pragma unroll
        for (int nt = 0; nt < 4; nt++) {
            bf16x8 bfr[2][2];
#pragma unroll
            for (int ng = 0; ng < 2; ng++)
#pragma unroll
                for (int ks = 0; ks < 2; ks++) {
                    int n = ng * 64 + nt * 16 + m16;
                    bfr[ng][ks] = *(const bf16x8*)(sh_wt + n * HS + ks * 32 + quad * 8);
                }
#pragma unroll
            for (int mt = 0; mt < 2; mt++) {
                f32x4 a0 = {0.f, 0.f, 0.f, 0.f};
                f32x4 a1 = {0.f, 0.f, 0.f, 0.f};
                a0 = __builtin_amdgcn_mfma_f32_16x16x32_bf16(afr[mt][0], bfr[0][0], a0, 0, 0, 0);
                a0 = __builtin_amdgcn_mfma_f32_16x16x32_bf16(afr[mt][1], bfr[0][1], a0, 0, 0, 0);
                a1 = __builtin_amdgcn_mfma_f32_16x16x32_bf16(afr[mt][0], bfr[1][0], a1, 0, 0, 0);
                a1 = __builtin_amdgcn_mfma_f32_16x16x32_bf16(afr[mt][1], bfr[1][1], a1, 0, 0, 0);
                int nidx = nt * 16 + m16;
#pragma unroll
                for (int r = 0; r < 4; r++) {
                    int e = e0 + wave * 32 + mt * 16 + quad * 4 + r;
                    if (e < E) {
                        unsigned lo = f2bf(a0[r] * 0.125f);
                        unsigned hi = f2bf(a1[r] * 0.125f);
                        w2_buf[(size_t)e * 64 + nidx] = lo | (hi << 16);
                    }
                }
            }
        }
    }
}

// node_fctp body: 16 nodes/block; smem: [0,16K) w0 | [16K,32K) w1 | [32K,35K) sh
__device__ __forceinline__ void node_fctp_body(
    int blk, int path,
    const float* __restrict__ s, const float* __restrict__ v,
    const float* __restrict__ attr, const float* __restrict__ Wfp,
    float* __restrict__ sc_s, float* __restrict__ sc_v,
    float* __restrict__ xsv, int N, char* smem) {
    float* w0 = (float*)smem;
    float* w1 = (float*)(smem + 16384);
    float (*sh)[96] = (float(*)[96])(smem + 32768);
    int ln = threadIdx.x >> 5, w = threadIdx.x & 31;
    const float4* W0p = (const float4*)(Wfp + path * 8192);
    const float4* W1p = (const float4*)(Wfp + path * 8192 + 4096);
    for (int i = threadIdx.x; i < 1024; i += 256) {
        ((float4*)w0)[i] = W0p[i];
        ((float4*)w1)[i] = W1p[i];
    }
    for (int g = 0; g < 2; g++) {
        int n = blk * 16 + g * 8 + ln;
        bool valid = n < N;
        __syncthreads();
        if (valid) {
            if (path == 0) {
                sh[ln][w] = s[n * 32 + w];
            } else {
                sh[ln][w * 3 + 0] = v[n * 96 + w * 3 + 0];
                sh[ln][w * 3 + 1] = v[n * 96 + w * 3 + 1];
                sh[ln][w * 3 + 2] = v[n * 96 + w * 3 + 2];
            }
        }
        __syncthreads();
        if (!valid) continue;
        float4 at = *(const float4*)(attr + n * 4);
        if (path == 0) {
            float acc0 = 0.f, acc1 = 0.f;
            for (int u = 0; u < 32; u++) {
                float su = sh[ln][u];
                float4 W0v = *(const float4*)(w0 + u * 128 + w * 4);
                float4 W1v = *(const float4*)(w1 + u * 128 + w * 4);
                float d0 = at.x * W0v.x + at.y * W0v.y + at.z * W0v.z + at.w * W0v.w;
                float d1 = at.x * W1v.x + at.y * W1v.y + at.z * W1v.z + at.w * W1v.w;
                acc0 += su * d0;
                acc1 += su * d1;
            }
            sc_s[n * 32 + w] = acc0 * NORM128_F;
            xsv[(size_t)n * 128 + w * 4 + 3] = acc1 * NORM128_F;
        } else {
            float a00 = 0, a01 = 0, a02 = 0, a10 = 0, a11 = 0, a12 = 0;
            for (int u = 0; u < 32; u++) {
                float vu0 = sh[ln][u * 3 + 0];
                float vu1 = sh[ln][u * 3 + 1];
                float vu2 = sh[ln][u * 3 + 2];
                float4 W0v = *(const float4*)(w0 + u * 128 + w * 4);
                float4 W1v = *(const float4*)(w1 + u * 128 + w * 4);
                float d0 = at.x * W0v.x + at.y * W0v.y + at.z * W0v.z + at.w * W0v.w;
                float d1 = at.x * W1v.x + at.y * W1v.y + at.z * W1v.z + at.w * W1v.w;
                a00 += vu0 * d0; a01 += vu1 * d0; a02 += vu2 * d0;
                a10 += vu0 * d1; a11 += vu1 * d1; a12 += vu2 * d1;
            }
            sc_v[n * 96 + w * 3 + 0] = a00 * NORM128_F;
            sc_v[n * 96 + w * 3 + 1] = a01 * NORM128_F;
            sc_v[n * 96 + w * 3 + 2] = a02 * NORM128_F;
            float* xp = xsv + (size_t)n * 128 + w * 4;
            xp[0] = a10 * NORM128_F;
            xp[1] = a11 * NORM128_F;
            xp[2] = a12 * NORM128_F;
        }
    }
}

// ---------------------------------------------------------------- fused stage
__global__ __launch_bounds__(256, 4) void fused_stage(
    int nE0, int nE1, int nFctpBlk,
    const float* __restrict__ vec_csr, const float* __restrict__ Wfc1,
    const unsigned* __restrict__ wt_g,
    unsigned* __restrict__ w2_0, unsigned* __restrict__ w2_1,
    const float* __restrict__ s, const float* __restrict__ v,
    const float* __restrict__ attr, const float* __restrict__ Wfp,
    float* __restrict__ sc_s, float* __restrict__ sc_v,
    float* __restrict__ xsv, int N, int E) {
    __shared__ __align__(16) char smem[39936];
    int b = blockIdx.x;
    if (b < nE0) {
        edge_weights_body(b, vec_csr, Wfc1, wt_g, w2_0, E, smem);
        return;
    }
    b -= nE0;
    if (b < nE1) {
        edge_weights_body(b, vec_csr, Wfc1 + 640, wt_g + 4096, w2_1, E, smem);
        return;
    }
    b -= nE1;
    node_fctp_body(b % nFctpBlk, b / nFctpBlk, s, v, attr, Wfp,
                   sc_s, sc_v, xsv, N, smem);
}

// ---------------------------------------------------------------- gather + update (fused)
// Block owns 2 nodes. Phase A: gather (2 waves/node, 4 quarter-waves).
// agg passes through LDS. Phase B: second fctp + s,v update for the same
// 2 nodes (4 u-quarters per (n,w), LDS reduce). No agg HBM round trip.
__global__ __launch_bounds__(256, 4) void gather_update(
    const int* __restrict__ off, const int* __restrict__ cnt,
    const unsigned* __restrict__ w2_buf, const float* __restrict__ vec_csr,
    const float* __restrict__ xsv, const unsigned* __restrict__ Wupk,
    const float* __restrict__ attr,
    const float* __restrict__ sc_s, const float* __restrict__ sc_v,
    float* __restrict__ s, float* __restrict__ v, int N) {
    __shared__ __align__(16) unsigned pk[8192];     // 32 KB packed update weights
    __shared__ float sh_agg[2][256];                // [node][0..63 s | 64..255 v]
    __shared__ __align__(16) float red4[4][2][32][4];  // update reduce; gather fold reuses

    int tid = threadIdx.x;
    for (int i = tid; i < 2048; i += 256)
        ((uint4*)pk)[i] = ((const uint4*)Wupk)[i];

    // ---- phase A: gather
    int pair = tid >> 7;
    int node = blockIdx.x * 2 + pair;
    int ql = tid & 127;
    int quarter = ql >> 5;
    int u = ql & 31;
    bool active = node < N;
    int o = 0, deg = 0;
    if (active) { o = off[node]; deg = cnt[node]; }
    float as0 = 0, as1 = 0;
    float av00 = 0, av01 = 0, av02 = 0, av10 = 0, av11 = 0, av12 = 0;

    auto body = [&](int slot) {
        size_t p = (size_t)slot;
        float4 vv = *(const float4*)(vec_csr + p * 4);
        int src = __float_as_int(vv.w);
        float len = sqrtf(vv.x * vv.x + vv.y * vv.y + vv.z * vv.z);
        float rinv = SQRT3_F / (len + 1e-9f);
        float y0 = vv.x * rinv, y1 = vv.y * rinv, y2 = vv.z * rinv;
        float4 x4 = *(const float4*)(xsv + (size_t)src * 128 + u * 4);
        unsigned q0 = w2_buf[p * 64 + u];
        unsigned q1 = w2_buf[p * 64 + 32 + u];
        float wa = bf2f((unsigned short)q0), wc = bf2f((unsigned short)(q0 >> 16));
        float wb = bf2f((unsigned short)q1), wd = bf2f((unsigned short)(q1 >> 16));
        as0 += wa * x4.w;
        as1 += wb * (y0 * x4.x + y1 * x4.y + y2 * x4.z) * INV_SQRT3_F;
        float t = wc * x4.w;
        av00 += t * y0;  av01 += t * y1;  av02 += t * y2;
        av10 += wd * x4.x; av11 += wd * x4.y; av12 += wd * x4.z;
    };

    int i = quarter;
    for (; i + 4 < deg; i += 8) { body(o + i); body(o + i + 4); }
    for (; i < deg; i += 4) body(o + i);

    as0 += __shfl_down(as0, 32);  as1 += __shfl_down(as1, 32);
    av00 += __shfl_down(av00, 32); av01 += __shfl_down(av01, 32); av02 += __shfl_down(av02, 32);
    av10 += __shfl_down(av10, 32); av11 += __shfl_down(av11, 32); av12 += __shfl_down(av12, 32);

    int lane = tid & 63;
    int upper_wave = (tid >> 6) & 1;
    float* redf = (float*)red4;                     // [pair][8][32] fold scratch
    if (upper_wave && lane < 32) {
        redf[(pair * 8 + 0) * 32 + u] = as0;  redf[(pair * 8 + 1) * 32 + u] = as1;
        redf[(pair * 8 + 2) * 32 + u] = av00; redf[(pair * 8 + 3) * 32 + u] = av01;
        redf[(pair * 8 + 4) * 32 + u] = av02; redf[(pair * 8 + 5) * 32 + u] = av10;
        redf[(pair * 8 + 6) * 32 + u] = av11; redf[(pair * 8 + 7) * 32 + u] = av12;
    }
    __syncthreads();
    if (!upper_wave && lane < 32) {
        as0  += redf[(pair * 8 + 0) * 32 + u];  as1  += redf[(pair * 8 + 1) * 32 + u];
        av00 += redf[(pair * 8 + 2) * 32 + u];  av01 += redf[(pair * 8 + 3) * 32 + u];
        av02 += redf[(pair * 8 + 4) * 32 + u];  av10 += redf[(pair * 8 + 5) * 32 + u];
        av11 += redf[(pair * 8 + 6) * 32 + u];  av12 += redf[(pair * 8 + 7) * 32 + u];
        float* ag = sh_agg[pair];
        ag[u]      = as0 * INV_SQRTNN_F;
        ag[32 + u] = as1 * INV_SQRTNN_F;
        ag[64 + u * 3 + 0] = av00 * INV_SQRTNN_F;
        ag[64 + u * 3 + 1] = av01 * INV_SQRTNN_F;
        ag[64 + u * 3 + 2] = av02 * INV_SQRTNN_F;
        ag[64 + (32 + u) * 3 + 0] = av10 * INV_SQRTNN_F;
        ag[64 + (32 + u) * 3 + 1] = av11 * INV_SQRTNN_F;
        ag[64 + (32 + u) * 3 + 2] = av12 * INV_SQRTNN_F;
    }
    __syncthreads();

    // ---- phase B: second fctp + update for the block's 2 nodes
    int q  = tid >> 6;              // u-quarter 0..3
    int nl = (tid >> 5) & 1;        // node slot
    int w  = tid & 31;
    int n2 = blockIdx.x * 2 + nl;
    float ps = 0.f, p0 = 0.f, p1 = 0.f, p2 = 0.f;
    if (n2 < N) {
        float4 at = *(const float4*)(attr + n2 * 4);
        const float* ag = sh_agg[nl];
#pragma unroll
        for (int uu = 0; uu < 16; uu++) {
            int ui = q * 16 + uu;
            float gs = ag[ui];
            float g0 = ag[64 + ui * 3 + 0];
            float g1 = ag[64 + ui * 3 + 1];
            float g2 = ag[64 + ui * 3 + 2];
            uint4 pv = *(const uint4*)(pk + ui * 128 + w * 4);
            float w20x = bf2f((unsigned short)pv.x), w21x = bf2f((unsigned short)(pv.x >> 16));
            float w20y = bf2f((unsigned short)pv.y), w21y = bf2f((unsigned short)(pv.y >> 16));
            float w20z = bf2f((unsigned short)pv.z), w21z = bf2f((unsigned short)(pv.z >> 16));
            float w20w = bf2f((unsigned short)pv.w), w21w = bf2f((unsigned short)(pv.w >> 16));
            float d0 = at.x * w20x + at.y * w20y + at.z * w20z + at.w * w20w;
            float d1 = at.x * w21x + at.y * w21y + at.z * w21z + at.w * w21w;
            ps += gs * d0;
            p0 += g0 * d1; p1 += g1 * d1; p2 += g2 * d1;
        }
    }
    __syncthreads();   // redf fold scratch no longer needed
    red4[q][nl][w][0] = ps; red4[q][nl][w][1] = p0;
    red4[q][nl][w][2] = p1; red4[q][nl][w][3] = p2;
    __syncthreads();
    if (tid < 64) {
        int nl2 = tid >> 5, w2 = tid & 31;
        int n3 = blockIdx.x * 2 + nl2;
        if (n3 < N) {
            float rs = 0.f, r0 = 0.f, r1 = 0.f, r2 = 0.f;
#pragma unroll
            for (int qq = 0; qq < 4; qq++) {
                rs += red4[qq][nl2][w2][0];
                r0 += red4[qq][nl2][w2][1];
                r1 += red4[qq][nl2][w2][2];
                r2 += red4[qq][nl2][w2][3];
            }
            float os = rs * NORM256_F;
            float sn = C_S_F * sc_s[n3 * 32 + w2] + C_X_F * os;
            float sig = 1.0f / (1.0f + __expf(-sn));
            s[n3 * 32 + w2] += sn * sig;   // silu(sn)
            float ov0 = r0 * NORM256_F, ov1 = r1 * NORM256_F, ov2 = r2 * NORM256_F;
            v[n3 * 96 + w2 * 3 + 0] += (C_S_F * sc_v[n3 * 96 + w2 * 3 + 0] + C_X_F * ov0) * sig;
            v[n3 * 96 + w2 * 3 + 1] += (C_S_F * sc_v[n3 * 96 + w2 * 3 + 1] + C_X_F * ov1) * sig;
            v[n3 * 96 + w2 * 3 + 2] += (C_S_F * sc_v[n3 * 96 + w2 * 3 + 2] + C_X_F * ov2) * sig;
        }
    }
}

// ---------------------------------------------------------------- readout
__global__ __launch_bounds__(256) void readout(
    const float* __restrict__ s, const float* __restrict__ attr,
    const float* __restrict__ Wread, const int* __restrict__ batch,
    float* __restrict__ out, int N, float pool_scale) {
    __shared__ float wr[2048];
    __shared__ float red[NGRAPH * 16];
    for (int i = threadIdx.x; i < 2048; i += 256) wr[i] = Wread[i];
    if (threadIdx.x < NGRAPH * 16) red[threadIdx.x] = 0.f;
    __syncthreads();
    int ln = threadIdx.x >> 4, w = threadIdx.x & 15;
    for (int g = 0; g < 4; g++) {
        int n = blockIdx.x * 64 + g * 16 + ln;
        if (n < N) {
            float4 at = *(const float4*)(attr + n * 4);
            float fa[4] = {at.x, at.y, at.z, at.w};
            float acc = 0.f;
            for (int u = 0; u < 32; u++) {
                float su = s[n * 32 + u];
                int base = u * 64 + w;
#pragma unroll
                for (int a = 0; a < 4; a++) acc += su * fa[a] * wr[base + a * 16];
            }
            atomicAdd(&red[batch[n] * 16 + w], acc);
        }
    }
    __syncthreads();
    if (threadIdx.x < NGRAPH * 16) {
        float val = red[threadIdx.x];
        if (val != 0.f)
            atomicAdd(&out[threadIdx.x], val * NORM128_F * pool_scale);
    }
}

// ---------------------------------------------------------------- launch
extern "C" void kernel_launch(void* const* d_in, const int* in_sizes, int n_in,
                              void* d_out, int out_size, void* d_ws, size_t ws_size,
                              hipStream_t stream) {
    const float* x        = (const float*)d_in[0];
    const float* nattr    = (const float*)d_in[1];
    const float* edge_vec = (const float*)d_in[2];
    const int*   batch    = (const int*)d_in[3];
    const int*   esrc     = (const int*)d_in[4];
    const int*   edst     = (const int*)d_in[5];
    const float* Wsc0  = (const float*)d_in[6];
    const float* Wsc1  = (const float*)d_in[7];
    const float* Wl10  = (const float*)d_in[8];
    const float* Wl11  = (const float*)d_in[9];
    const float* Wfc1  = (const float*)d_in[10];
    const float* Wfc2  = (const float*)d_in[11];
    const float* Wl20  = (const float*)d_in[12];
    const float* Wl21  = (const float*)d_in[13];
    const float* Wread = (const float*)d_in[14];

    int N = in_sizes[0] / (MUL * 4);
    int E = in_sizes[2] / 3;

    float* p = (float*)d_ws;
    unsigned* w2_0 = (unsigned*)p; p += (size_t)E * 64;  // layer-0 packed bf16 pairs
    unsigned* w2_1 = (unsigned*)p; p += (size_t)E * 64;  // layer-1 packed bf16 pairs
    float* vec_csr = p; p += (size_t)E * 4;     // {ex,ey,ez,src-bits}
    unsigned* wt_g = (unsigned*)p; p += 8192;   // 2 layers x 4096 packed dwords
    float* Wfp    = p; p += 32768;              // 2 layers x 4 matrices x 4096
    unsigned* Wupk = (unsigned*)p; p += 16384;  // 2 layers x 8192 packed pair dwords
    float* s_buf  = p; p += (size_t)N * 32;
    float* v_buf  = p; p += (size_t)N * 96;
    float* sc_s   = p; p += (size_t)N * 32;
    float* sc_v   = p; p += (size_t)N * 96;
    float* xsv    = p; p += (size_t)N * 128;    // {xv0,xv1,xv2,xs} per (n,u)
    int* cnt     = (int*)p; p += N;
    int* off     = (int*)p; p += N;
    int* cursor  = (int*)p; p += N;

    init_sv<<<(N * 128 + 255) / 256, 256, 0, stream>>>(x, s_buf, v_buf, N);
    hipMemsetAsync(d_out, 0, (size_t)out_size * sizeof(float), stream);
    setup_weights<<<224, 256, 0, stream>>>(Wfc2, Wsc0, Wl10, Wsc1, Wl11,
                                           Wl20, Wl21, wt_g, Wfp, Wupk);

    // CSR by destination; edge data scattered into CSR order once.
    hipMemsetAsync(cnt, 0, (size_t)N * sizeof(int), stream);
    csr_count<<<(E + 255) / 256, 256, 0, stream>>>(edst, cnt, E);
    csr_scan<<<1, 256, 0, stream>>>(cnt, off, cursor, N);
    csr_fill<<<(E + 255) / 256, 256, 0, stream>>>(
        edst, esrc, edge_vec, cursor, vec_csr, E);

    int nE = (E + 127) / 128;
    int nF = (N + 15) / 16;

    // ---- layer 0: edges(l0) || edges(l1) || fctp(l0) in one dispatch
    fused_stage<<<nE * 2 + nF * 2, 256, 0, stream>>>(
        nE, nE, nF, vec_csr, Wfc1, wt_g, w2_0, w2_1,
        s_buf, v_buf, nattr, Wfp, sc_s, sc_v, xsv, N, E);
    gather_update<<<(N + 1) / 2, 256, 0, stream>>>(
        off, cnt, w2_0, vec_csr, xsv, Wupk, nattr, sc_s, sc_v,
        s_buf, v_buf, N);

    // ---- layer 1: fctp only (edges already computed into w2_1)
    fused_stage<<<nF * 2, 256, 0, stream>>>(
        0, 0, nF, vec_csr, Wfc1, wt_g, w2_0, w2_1,
        s_buf, v_buf, nattr, Wfp + 16384, sc_s, sc_v, xsv, N, E);
    gather_update<<<(N + 1) / 2, 256, 0, stream>>>(
        off, cnt, w2_1, vec_csr, xsv, Wupk + 8192, nattr, sc_s, sc_v,
        s_buf, v_buf, N);

    float pool_scale = (float)(1.0 / sqrt((double)N / (double)NGRAPH));
    readout<<<(N + 63) / 64, 256, 0, stream>>>(
        s_buf, nattr, Wread, batch, (float*)d_out, N, pool_scale);
}

// Round 22
// 340.554 us; speedup vs baseline: 1.0583x; 1.0583x over previous
//
#include <hip/hip_runtime.h>
#include <math.h>

#define MUL 32
#define NATTR 4
#define NBASIS 10
#define HID 64
#define OUT_DIM 16
#define NGRAPH 8

#define PI_F 3.14159265358979323846f
#define SQRT3_F 1.7320508075688772f
#define INV_SQRT3_F 0.5773502691896258f
#define INV_SQRT10_F 0.31622776601683794f
#define INV_SQRTNN_F 0.17677669529663687f   // 1/sqrt(32)
#define NORM128_F 0.08838834764831845f      // 1/sqrt(128)
#define NORM256_F 0.0625f                   // 1/sqrt(256)
#define C_S_F 0.3826834323650898f           // sin(pi/8)
#define C_X_F 0.9238795325112867f           // cos(pi/8)
#define CSTEP_F (4.0f/9.0f)                 // linspace(0,4,10) step

#define HS 72    // bf16 row stride (shorts): 64 + 8 pad -> 144B, 16B-aligned

typedef __attribute__((ext_vector_type(8))) short bf16x8;
typedef __attribute__((ext_vector_type(4))) float f32x4;

__device__ inline unsigned short f2bf(float x) {
    unsigned u = __float_as_uint(x);
    u += 0x7FFF + ((u >> 16) & 1);          // round-to-nearest-even
    return (unsigned short)(u >> 16);
}
__device__ inline float bf2f(unsigned short h) {
    return __uint_as_float(((unsigned)h) << 16);
}

// ---------------------------------------------------------------- init s,v
__global__ void init_sv(const float* __restrict__ x,
                        float* __restrict__ s, float* __restrict__ v, int N) {
    int i = blockIdx.x * 256 + threadIdx.x;
    if (i >= N * 128) return;
    int n = i >> 7, c = i & 127;
    float val = x[i];
    if (c < 32) s[n * 32 + c] = val;
    else        v[n * 96 + (c - 32)] = val;
}

// ---------------------------------------------------------------- weight setup
// Fully parallel, 69632 elements:
//  [0, 4096)      : Wfc1 -> wfc1f MFMA B-fragments (K=32 padded from 10), bf16
//  [4096, 20480)  : Wfc2 -> wfc2f MFMA B-fragments [ng][nt][ks][lane][8], bf16
//  [20480, 53248) : fctp weights [u][a][w] -> Wfp [u][w*4+a] (2l x 4m), fp32
//  [53248, 69632) : update weights -> Wupk [u][w*4+a] packed (bf16,bf16)
__global__ void setup_weights(const float* __restrict__ Wfc1g,
                              const float* __restrict__ Wfc2,
                              const float* __restrict__ Wsc0, const float* __restrict__ Wl10,
                              const float* __restrict__ Wsc1, const float* __restrict__ Wl11,
                              const float* __restrict__ Wl20, const float* __restrict__ Wl21,
                              unsigned short* __restrict__ wfc1f,
                              unsigned short* __restrict__ wfc2f,
                              float* __restrict__ Wfp, unsigned* __restrict__ Wupk) {
    int i = blockIdx.x * 256 + threadIdx.x;
    if (i < 4096) {
        int l = i >> 11, r = i & 2047;
        int nt = r >> 9, lanej = r & 511;
        int lane = lanej >> 3, j = lanej & 7;
        int m16 = lane & 15, quad = lane >> 4;
        int k = quad * 8 + j, n = nt * 16 + m16;
        float val = (k < NBASIS) ? Wfc1g[l * 640 + k * 64 + n] : 0.f;
        wfc1f[i] = f2bf(val);
    } else if (i < 20480) {
        int i2 = i - 4096;
        int l = i2 >> 13, r = i2 & 8191;
        int f = r >> 9, lanej = r & 511;
        int lane = lanej >> 3, j = lanej & 7;
        int ng = f >> 3, nt = (f >> 1) & 3, ks = f & 1;
        int m16 = lane & 15, quad = lane >> 4;
        int k = ks * 32 + quad * 8 + j, n = ng * 64 + nt * 16 + m16;
        wfc2f[i2] = f2bf(Wfc2[l * 8192 + k * 128 + n]);
    } else if (i < 53248) {
        int j = i - 20480;
        int idx = j >> 12;          // l*4 + m
        int r = j & 4095;
        int l = idx >> 2, m = idx & 3;
        const float* base = (m == 0 ? Wsc0 : m == 1 ? Wl10 : m == 2 ? Wsc1 : Wl11)
                            + l * 4096;
        int u = r >> 7, rr = r & 127, a = rr >> 5, ww = rr & 31;
        Wfp[idx * 4096 + u * 128 + ww * 4 + a] = base[r];
    } else if (i < 69632) {
        int j = i - 53248;
        int l = j >> 13;
        int r = j & 8191;
        int u = r >> 7, rr = r & 127, a = rr >> 5, ww = rr & 31;
        unsigned lo = f2bf(Wl20[l * 8192 + r]);
        unsigned hi = f2bf(Wl21[l * 8192 + r]);
        Wupk[l * 8192 + u * 128 + ww * 4 + a] = lo | (hi << 16);
    }
}

// ---------------------------------------------------------------- CSR build
__global__ void csr_count(const int* __restrict__ edst, int* __restrict__ cnt, int E) {
    int e = blockIdx.x * 256 + threadIdx.x;
    if (e < E) atomicAdd(&cnt[edst[e]], 1);
}

__global__ void csr_scan(const int* __restrict__ cnt, int* __restrict__ off,
                         int* __restrict__ cursor, int N) {
    __shared__ int sums[256];
    int t = threadIdx.x;
    int chunk = (N + 255) / 256;
    int lo = t * chunk, hi = lo + chunk; if (hi > N) hi = N;
    int s = 0;
    for (int i = lo; i < hi; i++) s += cnt[i];
    sums[t] = s;
    __syncthreads();
    for (int d = 1; d < 256; d <<= 1) {
        int v = (t >= d) ? sums[t - d] : 0;
        __syncthreads();
        sums[t] += v;
        __syncthreads();
    }
    int run = (t == 0) ? 0 : sums[t - 1];
    for (int i = lo; i < hi; i++) {
        off[i] = run; cursor[i] = run;
        run += cnt[i];
    }
}

__global__ void csr_fill(const int* __restrict__ edst, const int* __restrict__ esrc,
                         const float* __restrict__ edge_vec,
                         int* __restrict__ cursor,
                         float* __restrict__ vec_csr, int E) {
    int e = blockIdx.x * 256 + threadIdx.x;
    if (e < E) {
        int p = atomicAdd(&cursor[edst[e]], 1);
        float4 vv = {edge_vec[e * 3 + 0], edge_vec[e * 3 + 1], edge_vec[e * 3 + 2],
                     __int_as_float(esrc[e])};
        *(float4*)(vec_csr + (size_t)p * 4) = vv;
    }
}

// ---------------------------------------------------------------- bodies
// edge_weights body: 128 CSR slots/block. Phase 1 and 2 both MFMA; B-operands
// loaded as pre-packed fragments from L2. smem: [0,512) len | [512,19456) sh_h.
__device__ __forceinline__ void edge_weights_body(
    int blk, const float* __restrict__ vec_csr,
    const unsigned short* __restrict__ wfc1f,
    const unsigned short* __restrict__ wfc2f,
    unsigned* __restrict__ w2_buf, int E, char* smem) {
    float* sh_len = (float*)smem;
    short* sh_h   = (short*)(smem + 512);

    int tid = threadIdx.x;
    int e0 = blk * 128;

    if (tid < 128) {
        int e = e0 + tid;
        float ex = 0.f, ey = 0.f, ez = 0.f;
        if (e < E) {
            float4 vv = *(const float4*)(vec_csr + (size_t)e * 4);
            ex = vv.x; ey = vv.y; ez = vv.z;
        }
        sh_len[tid] = sqrtf(ex * ex + ey * ey + ez * ez);
    }
    __syncthreads();

    int wave = tid >> 6, lane = tid & 63;
    int m16 = lane & 15, quad = lane >> 4;

    {   // ---- phase 1 (MFMA): h = silu((emb @ Wfc1)/sqrt(10)) -> bf16 sh_h
        bf16x8 bw1[4];
#pragma unroll
        for (int nt = 0; nt < 4; nt++)
            bw1[nt] = *(const bf16x8*)(wfc1f + nt * 512 + lane * 8);
#pragma unroll
        for (int mt = 0; mt < 2; mt++) {
            int e = wave * 32 + mt * 16 + m16;
            float len = sh_len[e];
            float uu = 2.0f * (len * 0.25f - 1.0f);
            float cut = (uu > 0.0f) ? 0.0f
                      : ((uu < -1.0f) ? 1.0f : 0.5f * (1.0f - __cosf(PI_F * uu)));
            bf16x8 afr;
#pragma unroll
            for (int j = 0; j < 8; j++) {
                int k = quad * 8 + j;
                float val = 0.f;
                if (k < NBASIS) {
                    float d = (len - k * CSTEP_F) * 2.5f;
                    val = __expf(-d * d) * cut;
                }
                afr[j] = (short)f2bf(val);
            }
#pragma unroll
            for (int nt = 0; nt < 4; nt++) {
                f32x4 acc = {0.f, 0.f, 0.f, 0.f};
                acc = __builtin_amdgcn_mfma_f32_16x16x32_bf16(afr, bw1[nt], acc, 0, 0, 0);
#pragma unroll
                for (int r = 0; r < 4; r++) {
                    float a = acc[r] * INV_SQRT10_F;
                    float h = a / (1.0f + __expf(-a));
                    int er = wave * 32 + mt * 16 + quad * 4 + r;
                    sh_h[er * HS + nt * 16 + m16] = (short)f2bf(h);
                }
            }
        }
    }
    __syncthreads();

    {   // ---- phase 2 (MFMA): w = (h @ Wfc2)/8, packed bf16 pair stores
        bf16x8 afr[2][2];
#pragma unroll
        for (int mt = 0; mt < 2; mt++)
#pragma unroll
            for (int ks = 0; ks < 2; ks++) {
                int e = wave * 32 + mt * 16 + m16;
                afr[mt][ks] = *(const bf16x8*)(sh_h + e * HS + ks * 32 + quad * 8);
            }
#pragma unroll
        for (int nt = 0; nt < 4; nt++) {
            bf16x8 bfr[2][2];
#pragma unroll
            for (int ng = 0; ng < 2; ng++)
#pragma unroll
                for (int ks = 0; ks < 2; ks++)
                    bfr[ng][ks] = *(const bf16x8*)(
                        wfc2f + (((ng * 4 + nt) * 2 + ks) * 64 + lane) * 8);
#pragma unroll
            for (int mt = 0; mt < 2; mt++) {
                f32x4 a0 = {0.f, 0.f, 0.f, 0.f};
                f32x4 a1 = {0.f, 0.f, 0.f, 0.f};
                a0 = __builtin_amdgcn_mfma_f32_16x16x32_bf16(afr[mt][0], bfr[0][0], a0, 0, 0, 0);
                a0 = __builtin_amdgcn_mfma_f32_16x16x32_bf16(afr[mt][1], bfr[0][1], a0, 0, 0, 0);
                a1 = __builtin_amdgcn_mfma_f32_16x16x32_bf16(afr[mt][0], bfr[1][0], a1, 0, 0, 0);
                a1 = __builtin_amdgcn_mfma_f32_16x16x32_bf16(afr[mt][1], bfr[1][1], a1, 0, 0, 0);
                int nidx = nt * 16 + m16;
#pragma unroll
                for (int r = 0; r < 4; r++) {
                    int e = e0 + wave * 32 + mt * 16 + quad * 4 + r;
                    if (e < E) {
                        unsigned lo = f2bf(a0[r] * 0.125f);
                        unsigned hi = f2bf(a1[r] * 0.125f);
                        w2_buf[(size_t)e * 64 + nidx] = lo | (hi << 16);
                    }
                }
            }
        }
    }
}

// node_fctp body: 16 nodes/block; smem: [0,16K) w0 | [16K,32K) w1 | [32K,35K) sh
__device__ __forceinline__ void node_fctp_body(
    int blk, int path,
    const float* __restrict__ s, const float* __restrict__ v,
    const float* __restrict__ attr, const float* __restrict__ Wfp,
    float* __restrict__ sc_s, float* __restrict__ sc_v,
    float* __restrict__ xsv, int N, char* smem) {
    float* w0 = (float*)smem;
    float* w1 = (float*)(smem + 16384);
    float (*sh)[96] = (float(*)[96])(smem + 32768);
    int ln = threadIdx.x >> 5, w = threadIdx.x & 31;
    const float4* W0p = (const float4*)(Wfp + path * 8192);
    const float4* W1p = (const float4*)(Wfp + path * 8192 + 4096);
    for (int i = threadIdx.x; i < 1024; i += 256) {
        ((float4*)w0)[i] = W0p[i];
        ((float4*)w1)[i] = W1p[i];
    }
    for (int g = 0; g < 2; g++) {
        int n = blk * 16 + g * 8 + ln;
        bool valid = n < N;
        __syncthreads();
        if (valid) {
            if (path == 0) {
                sh[ln][w] = s[n * 32 + w];
            } else {
                sh[ln][w * 3 + 0] = v[n * 96 + w * 3 + 0];
                sh[ln][w * 3 + 1] = v[n * 96 + w * 3 + 1];
                sh[ln][w * 3 + 2] = v[n * 96 + w * 3 + 2];
            }
        }
        __syncthreads();
        if (!valid) continue;
        float4 at = *(const float4*)(attr + n * 4);
        if (path == 0) {
            float acc0 = 0.f, acc1 = 0.f;
            for (int u = 0; u < 32; u++) {
                float su = sh[ln][u];
                float4 W0v = *(const float4*)(w0 + u * 128 + w * 4);
                float4 W1v = *(const float4*)(w1 + u * 128 + w * 4);
                float d0 = at.x * W0v.x + at.y * W0v.y + at.z * W0v.z + at.w * W0v.w;
                float d1 = at.x * W1v.x + at.y * W1v.y + at.z * W1v.z + at.w * W1v.w;
                acc0 += su * d0;
                acc1 += su * d1;
            }
            sc_s[n * 32 + w] = acc0 * NORM128_F;
            xsv[(size_t)n * 128 + w * 4 + 3] = acc1 * NORM128_F;
        } else {
            float a00 = 0, a01 = 0, a02 = 0, a10 = 0, a11 = 0, a12 = 0;
            for (int u = 0; u < 32; u++) {
                float vu0 = sh[ln][u * 3 + 0];
                float vu1 = sh[ln][u * 3 + 1];
                float vu2 = sh[ln][u * 3 + 2];
                float4 W0v = *(const float4*)(w0 + u * 128 + w * 4);
                float4 W1v = *(const float4*)(w1 + u * 128 + w * 4);
                float d0 = at.x * W0v.x + at.y * W0v.y + at.z * W0v.z + at.w * W0v.w;
                float d1 = at.x * W1v.x + at.y * W1v.y + at.z * W1v.z + at.w * W1v.w;
                a00 += vu0 * d0; a01 += vu1 * d0; a02 += vu2 * d0;
                a10 += vu0 * d1; a11 += vu1 * d1; a12 += vu2 * d1;
            }
            sc_v[n * 96 + w * 3 + 0] = a00 * NORM128_F;
            sc_v[n * 96 + w * 3 + 1] = a01 * NORM128_F;
            sc_v[n * 96 + w * 3 + 2] = a02 * NORM128_F;
            float* xp = xsv + (size_t)n * 128 + w * 4;
            xp[0] = a10 * NORM128_F;
            xp[1] = a11 * NORM128_F;
            xp[2] = a12 * NORM128_F;
        }
    }
}

// ---------------------------------------------------------------- fused stage
__global__ __launch_bounds__(256, 4) void fused_stage(
    int nE0, int nE1, int nFctpBlk,
    const float* __restrict__ vec_csr,
    const unsigned short* __restrict__ wfc1f,
    const unsigned short* __restrict__ wfc2f,
    unsigned* __restrict__ w2_0, unsigned* __restrict__ w2_1,
    const float* __restrict__ s, const float* __restrict__ v,
    const float* __restrict__ attr, const float* __restrict__ Wfp,
    float* __restrict__ sc_s, float* __restrict__ sc_v,
    float* __restrict__ xsv, int N, int E) {
    __shared__ __align__(16) char smem[35840];
    int b = blockIdx.x;
    if (b < nE0) {
        edge_weights_body(b, vec_csr, wfc1f, wfc2f, w2_0, E, smem);
        return;
    }
    b -= nE0;
    if (b < nE1) {
        edge_weights_body(b, vec_csr, wfc1f + 2048, wfc2f + 8192, w2_1, E, smem);
        return;
    }
    b -= nE1;
    node_fctp_body(b % nFctpBlk, b / nFctpBlk, s, v, attr, Wfp,
                   sc_s, sc_v, xsv, N, smem);
}

// ---------------------------------------------------------------- gather
// 2 waves per dst node (4 quarter-waves striding the edge list by 4).
__global__ __launch_bounds__(256, 4) void gather_msgs(
    const int* __restrict__ off, const int* __restrict__ cnt,
    const unsigned* __restrict__ w2_buf, const float* __restrict__ vec_csr,
    const float* __restrict__ xsv,
    float* __restrict__ agg_s, float* __restrict__ agg_v, int N) {
    __shared__ float red[2][8][32];
    int pair = threadIdx.x >> 7;
    int node = blockIdx.x * 2 + pair;
    int ql = threadIdx.x & 127;
    int quarter = ql >> 5;
    int u = ql & 31;
    bool active = node < N;
    int o = 0, deg = 0;
    if (active) { o = off[node]; deg = cnt[node]; }
    float as0 = 0, as1 = 0;
    float av00 = 0, av01 = 0, av02 = 0, av10 = 0, av11 = 0, av12 = 0;

    auto body = [&](int slot) {
        size_t p = (size_t)slot;
        float4 vv = *(const float4*)(vec_csr + p * 4);
        int src = __float_as_int(vv.w);
        float len = sqrtf(vv.x * vv.x + vv.y * vv.y + vv.z * vv.z);
        float rinv = SQRT3_F / (len + 1e-9f);
        float y0 = vv.x * rinv, y1 = vv.y * rinv, y2 = vv.z * rinv;
        float4 x4 = *(const float4*)(xsv + (size_t)src * 128 + u * 4);
        unsigned q0 = w2_buf[p * 64 + u];
        unsigned q1 = w2_buf[p * 64 + 32 + u];
        float wa = bf2f((unsigned short)q0), wc = bf2f((unsigned short)(q0 >> 16));
        float wb = bf2f((unsigned short)q1), wd = bf2f((unsigned short)(q1 >> 16));
        as0 += wa * x4.w;
        as1 += wb * (y0 * x4.x + y1 * x4.y + y2 * x4.z) * INV_SQRT3_F;
        float t = wc * x4.w;
        av00 += t * y0;  av01 += t * y1;  av02 += t * y2;
        av10 += wd * x4.x; av11 += wd * x4.y; av12 += wd * x4.z;
    };

    int i = quarter;
    for (; i + 4 < deg; i += 8) { body(o + i); body(o + i + 4); }
    for (; i < deg; i += 4) body(o + i);

    as0 += __shfl_down(as0, 32);  as1 += __shfl_down(as1, 32);
    av00 += __shfl_down(av00, 32); av01 += __shfl_down(av01, 32); av02 += __shfl_down(av02, 32);
    av10 += __shfl_down(av10, 32); av11 += __shfl_down(av11, 32); av12 += __shfl_down(av12, 32);

    int lane = threadIdx.x & 63;
    int upper_wave = (threadIdx.x >> 6) & 1;
    if (upper_wave && lane < 32) {
        red[pair][0][u] = as0;  red[pair][1][u] = as1;
        red[pair][2][u] = av00; red[pair][3][u] = av01; red[pair][4][u] = av02;
        red[pair][5][u] = av10; red[pair][6][u] = av11; red[pair][7][u] = av12;
    }
    __syncthreads();
    if (active && !upper_wave && lane < 32) {
        as0  += red[pair][0][u];  as1  += red[pair][1][u];
        av00 += red[pair][2][u];  av01 += red[pair][3][u];  av02 += red[pair][4][u];
        av10 += red[pair][5][u];  av11 += red[pair][6][u];  av12 += red[pair][7][u];
        agg_s[node * 64 + u]      = as0 * INV_SQRTNN_F;
        agg_s[node * 64 + 32 + u] = as1 * INV_SQRTNN_F;
        float* av = agg_v + (size_t)node * 192;
        av[u * 3 + 0]      = av00 * INV_SQRTNN_F;
        av[u * 3 + 1]      = av01 * INV_SQRTNN_F;
        av[u * 3 + 2]      = av02 * INV_SQRTNN_F;
        av[96 + u * 3 + 0] = av10 * INV_SQRTNN_F;
        av[96 + u * 3 + 1] = av11 * INV_SQRTNN_F;
        av[96 + u * 3 + 2] = av12 * INV_SQRTNN_F;
    }
}

// ------------------------------------------- merged second fctp + s,v update
__global__ __launch_bounds__(256, 4) void node_update(
    const float* __restrict__ agg_s, const float* __restrict__ agg_v,
    const float* __restrict__ attr, const unsigned* __restrict__ Wupk,
    const float* __restrict__ sc_s, const float* __restrict__ sc_v,
    float* __restrict__ s, float* __restrict__ v, int N) {
    __shared__ __align__(16) unsigned pk[8192];   // 32 KB: (bf16 W20, bf16 W21)
    __shared__ float sh_as[8][64];
    __shared__ float sh_av[8][192];
    int ln = threadIdx.x >> 5, w = threadIdx.x & 31;
    for (int i = threadIdx.x; i < 2048; i += 256)
        ((uint4*)pk)[i] = ((const uint4*)Wupk)[i];
    for (int g = 0; g < 2; g++) {
        int n = blockIdx.x * 16 + g * 8 + ln;
        bool valid = n < N;
        __syncthreads();
        if (valid) {
            sh_as[ln][w] = agg_s[n * 64 + w];
            sh_as[ln][32 + w] = agg_s[n * 64 + 32 + w];
#pragma unroll
            for (int i = 0; i < 6; i++)
                sh_av[ln][w * 6 + i] = agg_v[(size_t)n * 192 + w * 6 + i];
        }
        __syncthreads();
        if (!valid) continue;
        float4 at = *(const float4*)(attr + n * 4);
        float acc_s = 0.f, a0 = 0.f, a1 = 0.f, a2 = 0.f;
        for (int u = 0; u < 64; u++) {
            float gs = sh_as[ln][u];
            float g0 = sh_av[ln][u * 3 + 0];
            float g1 = sh_av[ln][u * 3 + 1];
            float g2 = sh_av[ln][u * 3 + 2];
            uint4 pv = *(const uint4*)(pk + u * 128 + w * 4);
            float w20x = bf2f((unsigned short)pv.x), w21x = bf2f((unsigned short)(pv.x >> 16));
            float w20y = bf2f((unsigned short)pv.y), w21y = bf2f((unsigned short)(pv.y >> 16));
            float w20z = bf2f((unsigned short)pv.z), w21z = bf2f((unsigned short)(pv.z >> 16));
            float w20w = bf2f((unsigned short)pv.w), w21w = bf2f((unsigned short)(pv.w >> 16));
            float d0 = at.x * w20x + at.y * w20y + at.z * w20z + at.w * w20w;
            float d1 = at.x * w21x + at.y * w21y + at.z * w21z + at.w * w21w;
            acc_s += gs * d0;
            a0 += g0 * d1; a1 += g1 * d1; a2 += g2 * d1;
        }
        float os = acc_s * NORM256_F;
        float sn = C_S_F * sc_s[n * 32 + w] + C_X_F * os;
        float sig = 1.0f / (1.0f + __expf(-sn));
        s[n * 32 + w] += sn * sig;   // silu(sn)
        float ov0 = a0 * NORM256_F, ov1 = a1 * NORM256_F, ov2 = a2 * NORM256_F;
        v[n * 96 + w * 3 + 0] += (C_S_F * sc_v[n * 96 + w * 3 + 0] + C_X_F * ov0) * sig;
        v[n * 96 + w * 3 + 1] += (C_S_F * sc_v[n * 96 + w * 3 + 1] + C_X_F * ov1) * sig;
        v[n * 96 + w * 3 + 2] += (C_S_F * sc_v[n * 96 + w * 3 + 2] + C_X_F * ov2) * sig;
    }
}

// ---------------------------------------------------------------- readout
__global__ __launch_bounds__(256) void readout(
    const float* __restrict__ s, const float* __restrict__ attr,
    const float* __restrict__ Wread, const int* __restrict__ batch,
    float* __restrict__ out, int N, float pool_scale) {
    __shared__ float wr[2048];
    __shared__ float red[NGRAPH * 16];
    for (int i = threadIdx.x; i < 2048; i += 256) wr[i] = Wread[i];
    if (threadIdx.x < NGRAPH * 16) red[threadIdx.x] = 0.f;
    __syncthreads();
    int ln = threadIdx.x >> 4, w = threadIdx.x & 15;
    for (int g = 0; g < 4; g++) {
        int n = blockIdx.x * 64 + g * 16 + ln;
        if (n < N) {
            float4 at = *(const float4*)(attr + n * 4);
            float fa[4] = {at.x, at.y, at.z, at.w};
            float acc = 0.f;
            for (int u = 0; u < 32; u++) {
                float su = s[n * 32 + u];
                int base = u * 64 + w;
#pragma unroll
                for (int a = 0; a < 4; a++) acc += su * fa[a] * wr[base + a * 16];
            }
            atomicAdd(&red[batch[n] * 16 + w], acc);
        }
    }
    __syncthreads();
    if (threadIdx.x < NGRAPH * 16) {
        float val = red[threadIdx.x];
        if (val != 0.f)
            atomicAdd(&out[threadIdx.x], val * NORM128_F * pool_scale);
    }
}

// ---------------------------------------------------------------- launch
extern "C" void kernel_launch(void* const* d_in, const int* in_sizes, int n_in,
                              void* d_out, int out_size, void* d_ws, size_t ws_size,
                              hipStream_t stream) {
    const float* x        = (const float*)d_in[0];
    const float* nattr    = (const float*)d_in[1];
    const float* edge_vec = (const float*)d_in[2];
    const int*   batch    = (const int*)d_in[3];
    const int*   esrc     = (const int*)d_in[4];
    const int*   edst     = (const int*)d_in[5];
    const float* Wsc0  = (const float*)d_in[6];
    const float* Wsc1  = (const float*)d_in[7];
    const float* Wl10  = (const float*)d_in[8];
    const float* Wl11  = (const float*)d_in[9];
    const float* Wfc1  = (const float*)d_in[10];
    const float* Wfc2  = (const float*)d_in[11];
    const float* Wl20  = (const float*)d_in[12];
    const float* Wl21  = (const float*)d_in[13];
    const float* Wread = (const float*)d_in[14];

    int N = in_sizes[0] / (MUL * 4);
    int E = in_sizes[2] / 3;

    float* p = (float*)d_ws;
    unsigned* w2_0 = (unsigned*)p; p += (size_t)E * 64;  // layer-0 packed bf16 pairs
    unsigned* w2_1 = (unsigned*)p; p += (size_t)E * 64;  // layer-1 packed bf16 pairs
    float* vec_csr = p; p += (size_t)E * 4;     // {ex,ey,ez,src-bits}
    unsigned short* wfc1f = (unsigned short*)p; p += 2048;  // 4096 bf16 frags (2 layers)
    unsigned short* wfc2f = (unsigned short*)p; p += 8192;  // 16384 bf16 frags (2 layers)
    float* Wfp    = p; p += 32768;              // 2 layers x 4 matrices x 4096
    unsigned* Wupk = (unsigned*)p; p += 16384;  // 2 layers x 8192 packed pair dwords
    float* s_buf  = p; p += (size_t)N * 32;
    float* v_buf  = p; p += (size_t)N * 96;
    float* sc_s   = p; p += (size_t)N * 32;
    float* sc_v   = p; p += (size_t)N * 96;
    float* xsv    = p; p += (size_t)N * 128;    // {xv0,xv1,xv2,xs} per (n,u)
    float* agg_s  = p; p += (size_t)N * 64;
    float* agg_v  = p; p += (size_t)N * 192;
    int* cnt     = (int*)p; p += N;
    int* off     = (int*)p; p += N;
    int* cursor  = (int*)p; p += N;

    init_sv<<<(N * 128 + 255) / 256, 256, 0, stream>>>(x, s_buf, v_buf, N);
    hipMemsetAsync(d_out, 0, (size_t)out_size * sizeof(float), stream);
    setup_weights<<<272, 256, 0, stream>>>(Wfc1, Wfc2, Wsc0, Wl10, Wsc1, Wl11,
                                           Wl20, Wl21, wfc1f, wfc2f, Wfp, Wupk);

    // CSR by destination; edge data scattered into CSR order once.
    hipMemsetAsync(cnt, 0, (size_t)N * sizeof(int), stream);
    csr_count<<<(E + 255) / 256, 256, 0, stream>>>(edst, cnt, E);
    csr_scan<<<1, 256, 0, stream>>>(cnt, off, cursor, N);
    csr_fill<<<(E + 255) / 256, 256, 0, stream>>>(
        edst, esrc, edge_vec, cursor, vec_csr, E);

    int nE = (E + 127) / 128;
    int nF = (N + 15) / 16;

    // ---- layer 0: edges(l0) || edges(l1) || fctp(l0) in one dispatch
    fused_stage<<<nE * 2 + nF * 2, 256, 0, stream>>>(
        nE, nE, nF, vec_csr, wfc1f, wfc2f, w2_0, w2_1,
        s_buf, v_buf, nattr, Wfp, sc_s, sc_v, xsv, N, E);
    gather_msgs<<<(N + 1) / 2, 256, 0, stream>>>(
        off, cnt, w2_0, vec_csr, xsv, agg_s, agg_v, N);
    node_update<<<nF, 256, 0, stream>>>(
        agg_s, agg_v, nattr, Wupk, sc_s, sc_v, s_buf, v_buf, N);

    // ---- layer 1: fctp only (edges already computed into w2_1)
    fused_stage<<<nF * 2, 256, 0, stream>>>(
        0, 0, nF, vec_csr, wfc1f, wfc2f, w2_0, w2_1,
        s_buf, v_buf, nattr, Wfp + 16384, sc_s, sc_v, xsv, N, E);
    gather_msgs<<<(N + 1) / 2, 256, 0, stream>>>(
        off, cnt, w2_1, vec_csr, xsv, agg_s, agg_v, N);
    node_update<<<nF, 256, 0, stream>>>(
        agg_s, agg_v, nattr, Wupk + 8192, sc_s, sc_v, s_buf, v_buf, N);

    float pool_scale = (float)(1.0 / sqrt((double)N / (double)NGRAPH));
    readout<<<(N + 63) / 64, 256, 0, stream>>>(
        s_buf, nattr, Wread, batch, (float*)d_out, N, pool_scale);
}